// Round 9
// baseline (37.722 us; speedup 1.0000x reference)
//
#include <hip/hip_runtime.h>

// Jacobi damped smoother: out = x + (w/k11) * (f - conv3x3(x, k)), zero padding.
// B=64, H=512, W=512, fp32.
// R8 structure (ROWS=4, shfl halos, hoisted loads, cached stores) + T1
// XCD-aware block swizzle: grid 2048 % 8 == 0, cb = (orig%8)*256 + orig/8
// gives each XCD a contiguous chunk -> adjacent strips (which re-read each
// other's halo rows) share an L2, converting L3 hits (~450cy) to L2 (~200cy).

#define ROWS 4

typedef float f32x4 __attribute__((ext_vector_type(4)));

__global__ __launch_bounds__(256) void jacobi_kernel(
    const float* __restrict__ x,
    const float* __restrict__ f,
    const float* __restrict__ kA,
    float* __restrict__ out)
{
    // XCD swizzle (8 XCDs, 2048 blocks -> 256-block contiguous chunk per XCD)
    const int orig = blockIdx.x;
    const int cb   = ((orig & 7) << 8) | (orig >> 3);

    const int lane = threadIdx.x & 63;
    const int wid  = (cb << 2) | (threadIdx.x >> 6);
    const int strip = wid & 127;        // 512 / ROWS = 128 strips per batch
    const int b     = wid >> 7;
    const int r0    = strip * ROWS;
    const int c0    = lane << 3;        // 8 columns per lane

    const size_t plane = (size_t)b << 18;       // 512*512
    const float* xb = x + plane;
    const float* fb = f + plane + ((size_t)r0 << 9) + c0;
    float*       ob = out + plane + ((size_t)r0 << 9) + c0;

    // ---- issue ALL loads upfront: 6 x-rows + 4 f-rows, vec4 pairs ----
    f32x4 xa[ROWS + 2], xc[ROWS + 2];
    #pragma unroll
    for (int q = 0; q < ROWS + 2; ++q) {
        const int r = r0 - 1 + q;               // wave-uniform validity
        if (r >= 0 && r < 512) {
            const float* p = xb + ((size_t)r << 9) + c0;
            xa[q] = *(const f32x4*)p;
            xc[q] = *(const f32x4*)(p + 4);
        } else {
            xa[q] = (f32x4){0.0f, 0.0f, 0.0f, 0.0f};
            xc[q] = (f32x4){0.0f, 0.0f, 0.0f, 0.0f};
        }
    }
    f32x4 fv[2 * ROWS];
    #pragma unroll
    for (int rr = 0; rr < ROWS; ++rr) {
        const float* fp = fb + ((size_t)rr << 9);
        fv[2 * rr]     = *(const f32x4*)fp;
        fv[2 * rr + 1] = *(const f32x4*)(fp + 4);
    }

    // per-batch 3x3 kernel (uniform across the wave -> scalar broadcast)
    const float* kb = kA + b * 9;
    const float k00 = kb[0], k01 = kb[1], k02 = kb[2];
    const float k10 = kb[3], k11 = kb[4], k12 = kb[5];
    const float k20 = kb[6], k21 = kb[7], k22 = kb[8];
    const float weight = (2.0f / 3.0f) / k11;

    // ---- unpack + halos via cross-lane shuffle (wave spans the full row) ----
    float xr[ROWS + 2][10];
    #pragma unroll
    for (int q = 0; q < ROWS + 2; ++q) {
        xr[q][1] = xa[q].x; xr[q][2] = xa[q].y; xr[q][3] = xa[q].z; xr[q][4] = xa[q].w;
        xr[q][5] = xc[q].x; xr[q][6] = xc[q].y; xr[q][7] = xc[q].z; xr[q][8] = xc[q].w;
        float left  = __shfl_up(xr[q][8], 1);
        float right = __shfl_down(xr[q][1], 1);
        xr[q][0] = (lane == 0)  ? 0.0f : left;   // image left edge -> 0
        xr[q][9] = (lane == 63) ? 0.0f : right;  // image right edge -> 0
    }

    // ---- per output row: stencil, store ----
    #pragma unroll
    for (int rr = 0; rr < ROWS; ++rr) {
        const float fx[8] = { fv[2*rr].x, fv[2*rr].y, fv[2*rr].z, fv[2*rr].w,
                              fv[2*rr+1].x, fv[2*rr+1].y, fv[2*rr+1].z, fv[2*rr+1].w };

        float res[8];
        #pragma unroll
        for (int p = 0; p < 8; ++p) {
            float Ax = k00 * xr[rr][p]     + k01 * xr[rr][p + 1]     + k02 * xr[rr][p + 2]
                     + k10 * xr[rr + 1][p] + k11 * xr[rr + 1][p + 1] + k12 * xr[rr + 1][p + 2]
                     + k20 * xr[rr + 2][p] + k21 * xr[rr + 2][p + 1] + k22 * xr[rr + 2][p + 2];
            res[p] = xr[rr + 1][p + 1] + weight * (fx[p] - Ax);
        }

        float* op = ob + ((size_t)rr << 9);
        f32x4 v0 = { res[0], res[1], res[2], res[3] };
        f32x4 v1 = { res[4], res[5], res[6], res[7] };
        *(f32x4*)op       = v0;
        *(f32x4*)(op + 4) = v1;
    }
}

extern "C" void kernel_launch(void* const* d_in, const int* in_sizes, int n_in,
                              void* d_out, int out_size, void* d_ws, size_t ws_size,
                              hipStream_t stream) {
    const float* x  = (const float*)d_in[0];
    const float* f  = (const float*)d_in[1];
    const float* kA = (const float*)d_in[2];
    float* out = (float*)d_out;

    // waves = 64 batches * 128 strips = 8192 ; threads = 524288 ; blocks = 2048
    const int total = 64 * (512 / ROWS) * 64;
    const int block = 256;
    const int grid  = total / block;
    jacobi_kernel<<<grid, block, 0, stream>>>(x, f, kA, out);
}

// Round 10
// 35.364 us; speedup vs baseline: 1.0667x; 1.0667x over previous
//
#include <hip/hip_runtime.h>

// Jacobi damped smoother: out = x + (w/k11) * (f - conv3x3(x, k)), zero padding.
// B=64, H=512, W=512, fp32.
// One wave covers a full 512-col row (8 cols/lane); halos via shfl, not memory.
// ROWS=4 rows per wave; all loads hoisted upfront for MLP; cached stores.
// Measured dead-ends on gfx950 (this problem): NT stores (+34% WRITE_SIZE, R6),
// XCD swizzle (-6%, R9), ROWS=1/2 (latency chain vs reuse tradeoff, R4/R5).
// Best measured: 35.6 us; physical traffic 136 MB ~= minimum (x+f fetch, out write).

#define ROWS 4

typedef float f32x4 __attribute__((ext_vector_type(4)));

__global__ __launch_bounds__(256) void jacobi_kernel(
    const float* __restrict__ x,
    const float* __restrict__ f,
    const float* __restrict__ kA,
    float* __restrict__ out)
{
    const int tid  = blockIdx.x * blockDim.x + threadIdx.x;
    const int lane = tid & 63;
    const int wid  = tid >> 6;
    const int strip = wid & 127;        // 512 / ROWS = 128 strips per batch
    const int b     = wid >> 7;
    const int r0    = strip * ROWS;
    const int c0    = lane << 3;        // 8 columns per lane

    const size_t plane = (size_t)b << 18;       // 512*512
    const float* xb = x + plane;
    const float* fb = f + plane + ((size_t)r0 << 9) + c0;
    float*       ob = out + plane + ((size_t)r0 << 9) + c0;

    // ---- issue ALL loads upfront: 6 x-rows + 4 f-rows, vec4 pairs ----
    f32x4 xa[ROWS + 2], xc[ROWS + 2];
    #pragma unroll
    for (int q = 0; q < ROWS + 2; ++q) {
        const int r = r0 - 1 + q;               // wave-uniform validity
        if (r >= 0 && r < 512) {
            const float* p = xb + ((size_t)r << 9) + c0;
            xa[q] = *(const f32x4*)p;
            xc[q] = *(const f32x4*)(p + 4);
        } else {
            xa[q] = (f32x4){0.0f, 0.0f, 0.0f, 0.0f};
            xc[q] = (f32x4){0.0f, 0.0f, 0.0f, 0.0f};
        }
    }
    f32x4 fv[2 * ROWS];
    #pragma unroll
    for (int rr = 0; rr < ROWS; ++rr) {
        const float* fp = fb + ((size_t)rr << 9);
        fv[2 * rr]     = *(const f32x4*)fp;
        fv[2 * rr + 1] = *(const f32x4*)(fp + 4);
    }

    // per-batch 3x3 kernel (uniform across the wave -> scalar broadcast)
    const float* kb = kA + b * 9;
    const float k00 = kb[0], k01 = kb[1], k02 = kb[2];
    const float k10 = kb[3], k11 = kb[4], k12 = kb[5];
    const float k20 = kb[6], k21 = kb[7], k22 = kb[8];
    const float weight = (2.0f / 3.0f) / k11;

    // ---- unpack + halos via cross-lane shuffle (wave spans the full row) ----
    float xr[ROWS + 2][10];
    #pragma unroll
    for (int q = 0; q < ROWS + 2; ++q) {
        xr[q][1] = xa[q].x; xr[q][2] = xa[q].y; xr[q][3] = xa[q].z; xr[q][4] = xa[q].w;
        xr[q][5] = xc[q].x; xr[q][6] = xc[q].y; xr[q][7] = xc[q].z; xr[q][8] = xc[q].w;
        float left  = __shfl_up(xr[q][8], 1);
        float right = __shfl_down(xr[q][1], 1);
        xr[q][0] = (lane == 0)  ? 0.0f : left;   // image left edge -> 0
        xr[q][9] = (lane == 63) ? 0.0f : right;  // image right edge -> 0
    }

    // ---- per output row: stencil, store ----
    #pragma unroll
    for (int rr = 0; rr < ROWS; ++rr) {
        const float fx[8] = { fv[2*rr].x, fv[2*rr].y, fv[2*rr].z, fv[2*rr].w,
                              fv[2*rr+1].x, fv[2*rr+1].y, fv[2*rr+1].z, fv[2*rr+1].w };

        float res[8];
        #pragma unroll
        for (int p = 0; p < 8; ++p) {
            float Ax = k00 * xr[rr][p]     + k01 * xr[rr][p + 1]     + k02 * xr[rr][p + 2]
                     + k10 * xr[rr + 1][p] + k11 * xr[rr + 1][p + 1] + k12 * xr[rr + 1][p + 2]
                     + k20 * xr[rr + 2][p] + k21 * xr[rr + 2][p + 1] + k22 * xr[rr + 2][p + 2];
            res[p] = xr[rr + 1][p + 1] + weight * (fx[p] - Ax);
        }

        float* op = ob + ((size_t)rr << 9);
        f32x4 v0 = { res[0], res[1], res[2], res[3] };
        f32x4 v1 = { res[4], res[5], res[6], res[7] };
        *(f32x4*)op       = v0;
        *(f32x4*)(op + 4) = v1;
    }
}

extern "C" void kernel_launch(void* const* d_in, const int* in_sizes, int n_in,
                              void* d_out, int out_size, void* d_ws, size_t ws_size,
                              hipStream_t stream) {
    const float* x  = (const float*)d_in[0];
    const float* f  = (const float*)d_in[1];
    const float* kA = (const float*)d_in[2];
    float* out = (float*)d_out;

    // waves = 64 batches * 128 strips = 8192 ; threads = 524288 ; blocks = 2048
    const int total = 64 * (512 / ROWS) * 64;
    const int block = 256;
    const int grid  = total / block;
    jacobi_kernel<<<grid, block, 0, stream>>>(x, f, kA, out);
}